// Round 9
// baseline (407.092 us; speedup 1.0000x reference)
//
#include <hip/hip_runtime.h>
#include <math.h>

// Problem constants
#define BB   2
#define SS   1024
#define HH   4096
#define NHH  32
#define NKVV 8
#define HDD  128
#define MR   2048   // B*S
#define KVD  1024   // NKV*HD
#define NQKVD 6144  // H + 2*KVD
#define KD   4096
// 1/sqrt(128) * log2(e): attention scores produced directly in exp2 domain
#define SCALE2_F 0.12751744f

typedef __attribute__((ext_vector_type(8))) short bf16x8;
typedef __attribute__((ext_vector_type(4))) float f32x4;
typedef __attribute__((ext_vector_type(4))) int i32x4;

#define MFMA(a, b, c) __builtin_amdgcn_mfma_f32_16x16x32_bf16((a), (b), (c), 0, 0, 0)
#define MFMA_I8(a, b, c) __builtin_amdgcn_mfma_i32_16x16x64_i8((a), (b), (c), 0, 0, 0)

__device__ __forceinline__ unsigned short f2bf(float f) {
  union { float f; unsigned u; } v; v.f = f;
  return (unsigned short)((v.u + 0x7fffu + ((v.u >> 16) & 1u)) >> 16);
}
__device__ __forceinline__ float bf2f(unsigned short s) {
  union { unsigned u; float f; } v; v.u = ((unsigned)s) << 16; return v.f;
}
// 2^x via the hardware transcendental (v_exp_f32 IS exp2)
__device__ __forceinline__ float exp2_fast(float x) {
  float r; asm("v_exp_f32 %0, %1" : "=v"(r) : "v"(x)); return r;
}
// pack two f32 -> packed bf16 pair (lo = s0, hi = s1), single instruction
__device__ __forceinline__ unsigned cvt_pk_bf16(float a, float b) {
  unsigned r; asm("v_cvt_pk_bf16_f32 %0, %1, %2" : "=v"(r) : "v"(a), "v"(b)); return r;
}

__device__ __forceinline__ void gload_lds16(const void* g, void* l) {
  __builtin_amdgcn_global_load_lds(
      (const __attribute__((address_space(1))) void*)g,
      (__attribute__((address_space(3))) void*)l, 16, 0, 0);
}

__device__ __forceinline__ signed char q8(float x, float inv) {
  float r = rintf(x * inv);
  r = fmaxf(-127.f, fminf(127.f, r));
  return (signed char)(int)r;
}

// ---------------- fused prep: weight cvt (all 4 matrices) + activation quant ----------------
// Round 13: rounds 7/8 proved the cvt path is NOT coalescing-bound (64B-stride
// vs perfect coalescing: identical 81us, 1.85 TB/s, VALU 8%). VGPR_Count=16 ->
// the 4-iteration load/pack/store chain was near-serial (Little's law: ~5
// outstanding loads/wave gives exactly ~1.8 TB/s at ~600cy latency). Fix = ILP:
// each thread BATCHES 16 independent int4 loads into registers (~80 VGPR, still
// 6 waves/SIMD), then 16 packed-dword stores. ~16 loads in flight/wave ->
// ~6KB/CU in flight -> ~5-6 TB/s by Little's law.
// Weight blocks: 2560 x 4096 chunks (all region boundaries divide 4096 ->
// block-uniform branch). Blocks [2560, 4608): x row-quant (proven body).
#define NQ4 ((size_t)HH * HH / 4)
#define NK4 ((size_t)KVD * HH / 4)
__global__ void prep_all(const int* __restrict__ wq, const int* __restrict__ wk,
                         const int* __restrict__ wv, const int* __restrict__ wo,
                         signed char* __restrict__ wqkv, signed char* __restrict__ wo8,
                         const float* __restrict__ x, signed char* __restrict__ x_i8,
                         float* __restrict__ scale) {
  __shared__ float wm[4];
  const int t = threadIdx.x;
  if (blockIdx.x < 2560) {
    const size_t c0 = (size_t)blockIdx.x * 4096;   // block-uniform region select
    const int4* src;
    unsigned* dst;
    size_t off0;
    if (c0 < NQ4) { src = (const int4*)wq; dst = (unsigned*)wqkv; off0 = c0; }
    else if (c0 < NQ4 + NK4) { src = (const int4*)wk; dst = (unsigned*)wqkv + NQ4; off0 = c0 - NQ4; }
    else if (c0 < NQ4 + 2 * NK4) { src = (const int4*)wv; dst = (unsigned*)wqkv + NQ4 + NK4; off0 = c0 - NQ4 - NK4; }
    else { src = (const int4*)wo; dst = (unsigned*)wo8; off0 = c0 - NQ4 - 2 * NK4; }
    off0 += t;
    int4 v[16];
#pragma unroll
    for (int j = 0; j < 16; ++j) v[j] = src[off0 + j * 256];   // 16 loads in flight
#pragma unroll
    for (int j = 0; j < 16; ++j)
      dst[off0 + j * 256] = (v[j].x & 0xff) | ((v[j].y & 0xff) << 8) |
                            ((v[j].z & 0xff) << 16) | (v[j].w << 24);
  } else {
    const int row = blockIdx.x - 2560;
    const float4* p = (const float4*)(x + (size_t)row * HH) + t * 4;
    float4 v[4];
    float m = 0.f;
#pragma unroll
    for (int j = 0; j < 4; ++j) {
      v[j] = p[j];
      m = fmaxf(m, fmaxf(fmaxf(fabsf(v[j].x), fabsf(v[j].y)), fmaxf(fabsf(v[j].z), fabsf(v[j].w))));
    }
#pragma unroll
    for (int o = 32; o; o >>= 1) m = fmaxf(m, __shfl_xor(m, o));
    if ((t & 63) == 0) wm[t >> 6] = m;
    __syncthreads();
    m = fmaxf(fmaxf(wm[0], wm[1]), fmaxf(wm[2], wm[3]));
    m = fmaxf(m, 1e-12f);
    const float inv = 127.f / m;
    union { signed char c[16]; int4 q; } o;
#pragma unroll
    for (int j = 0; j < 4; ++j) {
      o.c[j * 4 + 0] = q8(v[j].x, inv); o.c[j * 4 + 1] = q8(v[j].y, inv);
      o.c[j * 4 + 2] = q8(v[j].z, inv); o.c[j * 4 + 3] = q8(v[j].w, inv);
    }
    ((int4*)(x_i8 + (size_t)row * HH))[t] = o.q;
    if (t == 0) scale[row] = m / 127.f;
  }
}

__global__ void quant_bf16(const unsigned short* __restrict__ in, signed char* __restrict__ out,
                           float* __restrict__ scale) {
  __shared__ float wm[4];
  const int row = blockIdx.x;
  const int t = threadIdx.x;
  const uint4* p = (const uint4*)(in + (size_t)row * HH) + t * 2;
  float f[16];
  float m = 0.f;
#pragma unroll
  for (int j = 0; j < 2; ++j) {
    uint4 d = p[j];
    unsigned u[4] = {d.x, d.y, d.z, d.w};
#pragma unroll
    for (int k = 0; k < 4; ++k) {
      f[j * 8 + k * 2] = bf2f((unsigned short)(u[k] & 0xffff));
      f[j * 8 + k * 2 + 1] = bf2f((unsigned short)(u[k] >> 16));
    }
  }
#pragma unroll
  for (int e = 0; e < 16; ++e) m = fmaxf(m, fabsf(f[e]));
#pragma unroll
  for (int o = 32; o; o >>= 1) m = fmaxf(m, __shfl_xor(m, o));
  if ((t & 63) == 0) wm[t >> 6] = m;
  __syncthreads();
  m = fmaxf(fmaxf(wm[0], wm[1]), fmaxf(wm[2], wm[3]));
  m = fmaxf(m, 1e-12f);
  const float inv = 127.f / m;
  union { signed char c[16]; int4 q; } o;
#pragma unroll
  for (int e = 0; e < 16; ++e) o.c[e] = q8(f[e], inv);
  ((int4*)(out + (size_t)row * HH))[t] = o.q;
  if (t == 0) scale[row] = m / 127.f;
}

// ---------------- i8 GEMM, full-K, fused epilogue (round-5 proven body) ----------------
// Round-6 counted-vmcnt dbuf REGRESSED (79.5->86.3us, VALUBusy 19->34): the
// asm("+v") offset laundering forced dynamic LDS addressing (no immediate
// folding). This 2-barrier 32KB form = the 128-tile structure's ceiling
// (1.30 POPS, 33% of i8 peak; the stall is the structural barrier drain).
// 128x128 tile, BK=128, XOR-swizzled staging (source column chunk ^= row&7,
// LDS dest linear per global_load_lds rule; reads de-swizzle -> conflict-free).
// MODE 0: QKV fused epilogue (Q bias+scale, K bias, V transposed). MODE 1: O f32.
template <int MODE>
__global__ __launch_bounds__(256) void gemm_i8(
    const signed char* __restrict__ A, const signed char* __restrict__ W,
    const float* __restrict__ sRow,
    const float* __restrict__ s0, const float* __restrict__ s1, const float* __restrict__ s2,
    const float* __restrict__ bQ, const float* __restrict__ bK,
    unsigned short* __restrict__ oQ, unsigned short* __restrict__ oK,
    unsigned short* __restrict__ oVt, float* __restrict__ oF) {
  __shared__ signed char ldsA[128 * 128];
  __shared__ signed char ldsB[128 * 128];
  const int t = threadIdx.x;
  const int lane = t & 63;
  const int w = t >> 6;
  const int wr = w & 1, wc = w >> 1;
  const int l15 = lane & 15, quad = lane >> 4;
  const int bm = blockIdx.y, bn = blockIdx.x;

  const int srow_ = t >> 3;                          // 0..31
  const int scol_ = ((t & 7) ^ (srow_ & 7)) * 16;    // XOR-swizzled source column
  const signed char* gA = A + (size_t)(bm * 128 + srow_) * KD + scol_;
  const signed char* gW = W + (size_t)(bn * 128 + srow_) * KD + scol_;
  signed char* lA = ldsA + t * 16;  // wave base + lane*16 (global_load_lds layout rule)
  signed char* lB = ldsB + t * 16;

  i32x4 acc[4][4] = {};

  for (int k0 = 0; k0 < KD; k0 += 128) {
    __syncthreads();
#pragma unroll
    for (int j = 0; j < 4; ++j) {
      gload_lds16(gA + (size_t)j * 32 * KD + k0, lA + j * 4096);
      gload_lds16(gW + (size_t)j * 32 * KD + k0, lB + j * 4096);
    }
    __syncthreads();
#pragma unroll
    for (int kc = 0; kc < 2; ++kc) {
      i32x4 af[4], bfr[4];
#pragma unroll
      for (int mi = 0; mi < 4; ++mi) {
        const int row = wr * 64 + mi * 16 + l15;
        const int ch = (kc * 4 + quad) ^ (row & 7);
        af[mi] = *(const i32x4*)(ldsA + row * 128 + ch * 16);
      }
#pragma unroll
      for (int ni = 0; ni < 4; ++ni) {
        const int row = wc * 64 + ni * 16 + l15;
        const int ch = (kc * 4 + quad) ^ (row & 7);
        bfr[ni] = *(const i32x4*)(ldsB + row * 128 + ch * 16);
      }
#pragma unroll
      for (int mi = 0; mi < 4; ++mi)
#pragma unroll
        for (int ni = 0; ni < 4; ++ni)
          acc[mi][ni] = MFMA_I8(af[mi], bfr[ni], acc[mi][ni]);
    }
  }

  // C/D layout: row = quad*4 + r, col = lane&15 (dtype-independent, m121-128)
  const int row0 = bm * 128 + wr * 64 + quad * 4;
  const int col0 = bn * 128 + wc * 64 + l15;
  if (MODE == 1) {
    // O-projection: write f32 final output directly
#pragma unroll
    for (int ni = 0; ni < 4; ++ni) {
      const int col = col0 + ni * 16;
      const float sc = s0[col];
#pragma unroll
      for (int mi = 0; mi < 4; ++mi)
#pragma unroll
        for (int r = 0; r < 4; ++r) {
          const int row = row0 + mi * 16 + r;
          oF[(size_t)row * HH + col] = (float)acc[mi][ni][r] * sRow[row] * sc;
        }
    }
  } else if (col0 < HH) {
    // Q region: (v + bias) * log2e/sqrt(d), bf16 (exp2-domain pre-scale)
#pragma unroll
    for (int ni = 0; ni < 4; ++ni) {
      const int col = col0 + ni * 16;
      const float sc = s0[col];
      const float bv = bQ[col];
#pragma unroll
      for (int mi = 0; mi < 4; ++mi)
#pragma unroll
        for (int r = 0; r < 4; ++r) {
          const int row = row0 + mi * 16 + r;
          oQ[(size_t)row * HH + col] =
              f2bf(((float)acc[mi][ni][r] * sRow[row] * sc + bv) * SCALE2_F);
        }
    }
  } else if (col0 < HH + KVD) {
    // K region: + bias, bf16
#pragma unroll
    for (int ni = 0; ni < 4; ++ni) {
      const int col = col0 + ni * 16;
      const float sc = s1[col - HH];
      const float bv = bK[col - HH];
#pragma unroll
      for (int mi = 0; mi < 4; ++mi)
#pragma unroll
        for (int r = 0; r < 4; ++r) {
          const int row = row0 + mi * 16 + r;
          oK[(size_t)row * KVD + (col - HH)] =
              f2bf((float)acc[mi][ni][r] * sRow[row] * sc + bv);
        }
    }
  } else {
    // V region: write TRANSPOSED into Vt[col][row]; lane's 4 r-rows are
    // consecutive -> one 8B store per (mi,ni) fragment.
#pragma unroll
    for (int ni = 0; ni < 4; ++ni) {
      const int c = col0 + ni * 16 - (HH + KVD);
      const float sc = s2[c];
#pragma unroll
      for (int mi = 0; mi < 4; ++mi) {
        union { unsigned short s[4]; unsigned long long d; } pk;
#pragma unroll
        for (int r = 0; r < 4; ++r) {
          const int row = row0 + mi * 16 + r;
          pk.s[r] = f2bf((float)acc[mi][ni][r] * sRow[row] * sc);
        }
        *(unsigned long long*)(oVt + (size_t)c * MR + row0 + mi * 16) = pk.d;
      }
    }
  }
}

// ---------------- flash attention: 4-wave blocks, 64-row Q tile ----------------
// Round-4 verified: softmax chain cuts (cvt_pk pack, exp2 domain, diagonal-only
// mask, defer-max THR=8, lane-local l, setprio) dropped attn out of the top-5
// (<69us from 78.5). Structure: single-barrier double-buffered K+V LDS pipeline.
// Q pre-scaled by log2e/sqrt(d) in the QKV gemm epilogue; scores are exp2-domain.
__global__ __launch_bounds__(256, 2) void attn_kernel(
    const unsigned short* __restrict__ Q,   // [2048][4096]
    const unsigned short* __restrict__ K,   // [2048][1024]
    const unsigned short* __restrict__ Vt,  // [1024][2048]
    unsigned short* __restrict__ O) {       // [2048][4096]
  __shared__ unsigned short ldsK[2][64][128];   // K tiles (source-swizzled), 32 KB
  __shared__ unsigned short ldsV[2][2 * 128 * 32];  // V tiles [kc][hd][32], 32 KB
  __shared__ unsigned short ldsP[4][16 * 88];   // per-wave P tile 11 KB
  const int t = threadIdx.x;
  const int lane = t & 63;
  const int wv = t >> 6;
  const int l15 = lane & 15, quad = lane >> 4;
  const int qt = 15 - blockIdx.x;  // heavy-first
  const int h = blockIdx.y;
  const int b = blockIdx.z;
  const int kv = h >> 2;
  const int q0w = qt * 64 + wv * 16;
  const int q = q0w + l15;

  bf16x8 bq[4];
  const unsigned short* qbase = Q + (size_t)(b * SS + q0w + l15) * HH + h * HDD + quad * 8;
#pragma unroll
  for (int kk = 0; kk < 4; ++kk) bq[kk] = *(const bf16x8*)(qbase + kk * 32);

  const int srow = t >> 4;                        // 0..15
  const int schunk = (t & 15) ^ (srow & 7);       // pre-swizzled source chunk
  const unsigned short* gK = K + (size_t)(b * SS + srow) * KVD + kv * HDD + schunk * 8;
  const unsigned short* gV = Vt + (size_t)(kv * HDD + wv * 32 + (lane >> 2)) * MR + b * SS + (lane & 3) * 8;
  unsigned short* lV = &ldsV[0][0] + wv * 1024 + lane * 8;
  unsigned short* lp = ldsP[wv];

  f32x4 accO[8] = {};
  float m_run = -1e30f, l_part = 0.f;

  // prologue: stage tile 0 (K and V) into buf 0 (__syncthreads drains vmcnt)
#pragma unroll
  for (int j = 0; j < 4; ++j)
    gload_lds16(gK + (size_t)j * 16 * KVD, &ldsK[0][j * 16][0] + t * 8);
#pragma unroll
  for (int kc = 0; kc < 2; ++kc)
#pragma unroll
    for (int j = 0; j < 2; ++j)
      gload_lds16(gV + (size_t)j * 16 * MR + kc * 32, lV + kc * 4096 + j * 512);
  __syncthreads();

  int cur = 0;
  for (int kt = 0; kt <= qt; ++kt) {
    const int k0 = kt * 64;
    // prefetch NEXT tile (K and V) into the other buffers
    if (kt < qt) {
#pragma unroll
      for (int j = 0; j < 4; ++j)
        gload_lds16(gK + (size_t)(k0 + 64 + j * 16) * KVD,
                    &ldsK[cur ^ 1][j * 16][0] + t * 8);
#pragma unroll
      for (int kc = 0; kc < 2; ++kc)
#pragma unroll
        for (int j = 0; j < 2; ++j)
          gload_lds16(gV + (size_t)j * 16 * MR + k0 + 64 + kc * 32,
                      lV + (cur ^ 1) * 8192 + kc * 4096 + j * 512);
    }

    // QK^T from ldsK[cur] (de-swizzled read)
    f32x4 st[4] = {};
    __builtin_amdgcn_s_setprio(1);
#pragma unroll
    for (int kk = 0; kk < 4; ++kk)
#pragma unroll
      for (int mf = 0; mf < 4; ++mf) {
        const int r = mf * 16 + l15;
        bf16x8 af = *(const bf16x8*)(&ldsK[cur][r][((kk * 4 + quad) ^ (r & 7)) * 8]);
        st[mf] = MFMA(af, bq[kk], st[mf]);
      }
    __builtin_amdgcn_s_setprio(0);

    float p[4][4];
#pragma unroll
    for (int mf = 0; mf < 4; ++mf)
#pragma unroll
      for (int r = 0; r < 4; ++r) p[mf][r] = st[mf][r];
    if (kt == qt) {  // causal mask only on the diagonal tile
#pragma unroll
      for (int mf = 0; mf < 4; ++mf)
#pragma unroll
        for (int r = 0; r < 4; ++r) {
          const int k = k0 + mf * 16 + quad * 4 + r;
          if (k > q) p[mf][r] = -1e30f;
        }
    }
    float cm = -1e30f;
#pragma unroll
    for (int mf = 0; mf < 4; ++mf)
#pragma unroll
      for (int r = 0; r < 4; ++r) cm = fmaxf(cm, p[mf][r]);
    cm = fmaxf(cm, __shfl_xor(cm, 16));
    cm = fmaxf(cm, __shfl_xor(cm, 32));

    // defer-max (T13): rescale only when some row's max grew past THR=8
    if (!__all(cm <= m_run + 8.f)) {
      const float mn = fmaxf(m_run, cm);
      const float al = exp2_fast(m_run - mn);
      l_part *= al;
      m_run = mn;
      float af4[4];
#pragma unroll
      for (int r = 0; r < 4; ++r) af4[r] = __shfl(al, quad * 4 + r);
#pragma unroll
      for (int cb = 0; cb < 8; ++cb)
#pragma unroll
        for (int r = 0; r < 4; ++r) accO[cb][r] *= af4[r];
    }

    // exp2 + lane-local l + cvt_pk pack (8 insts, was ~80)
#pragma unroll
    for (int mf = 0; mf < 4; ++mf) {
      const float e0 = exp2_fast(p[mf][0] - m_run);
      const float e1 = exp2_fast(p[mf][1] - m_run);
      const float e2 = exp2_fast(p[mf][2] - m_run);
      const float e3 = exp2_fast(p[mf][3] - m_run);
      l_part += (e0 + e1) + (e2 + e3);
      union { unsigned u[2]; unsigned long long d; } pk;
      pk.u[0] = cvt_pk_bf16(e0, e1);
      pk.u[1] = cvt_pk_bf16(e2, e3);
      *(unsigned long long*)(lp + l15 * 88 + mf * 16 + quad * 4) = pk.d;
    }
    bf16x8 ap0 = *(const bf16x8*)(lp + l15 * 88 + quad * 8);
    bf16x8 ap1 = *(const bf16x8*)(lp + l15 * 88 + 32 + quad * 8);

    // PV from ldsV[cur]
    __builtin_amdgcn_s_setprio(1);
#pragma unroll
    for (int cb = 0; cb < 8; ++cb) {
      bf16x8 bv0 = *(const bf16x8*)(&ldsV[cur][0] + (cb * 16 + l15) * 32 + quad * 8);
      bf16x8 bv1 = *(const bf16x8*)(&ldsV[cur][0] + 4096 + (cb * 16 + l15) * 32 + quad * 8);
      accO[cb] = MFMA(ap0, bv0, accO[cb]);
      accO[cb] = MFMA(ap1, bv1, accO[cb]);
    }
    __builtin_amdgcn_s_setprio(0);

    __syncthreads();
    cur ^= 1;
  }

  // final l reduce (once, not per tile)
  l_part += __shfl_xor(l_part, 16);
  l_part += __shfl_xor(l_part, 32);
  float lr[4];
#pragma unroll
  for (int r = 0; r < 4; ++r) lr[r] = __shfl(l_part, quad * 4 + r);
  unsigned short* ob = O + (size_t)(b * SS + q0w + quad * 4) * HH + h * HDD + l15;
#pragma unroll
  for (int cb = 0; cb < 8; ++cb)
#pragma unroll
    for (int r = 0; r < 4; ++r)
      ob[(size_t)r * HH + cb * 16] = f2bf(accO[cb][r] / lr[r]);
}

extern "C" void kernel_launch(void* const* d_in, const int* in_sizes, int n_in,
                              void* d_out, int out_size, void* d_ws, size_t ws_size,
                              hipStream_t stream) {
  const float* x = (const float*)d_in[0];
  const int* wq = (const int*)d_in[2];
  const float* wqs = (const float*)d_in[3];
  const float* bq = (const float*)d_in[4];
  const int* wk = (const int*)d_in[5];
  const float* wks = (const float*)d_in[6];
  const float* bk = (const float*)d_in[7];
  const int* wv = (const int*)d_in[8];
  const float* wvs = (const float*)d_in[9];
  const int* wo = (const int*)d_in[10];
  const float* wos = (const float*)d_in[11];
  float* out = (float*)d_out;
  char* ws = (char*)d_ws;

  // workspace (MiB offsets), overlap-free:
  signed char*    x_i8    = (signed char*)   (ws + (0ull   << 20)); // 8   [prep, qkv-gemm]
  signed char*    wqkv_i8 = (signed char*)   (ws + (8ull   << 20)); // 24  [prep, qkv-gemm]
  signed char*    wo_i8   = (signed char*)   (ws + (32ull  << 20)); // 16  [prep, o-gemm]
  unsigned short* q_bf    = (unsigned short*)(ws + (48ull  << 20)); // 16  [qkv-gemm, attn]
  unsigned short* k_bf    = (unsigned short*)(ws + (64ull  << 20)); // 4   [qkv-gemm, attn]
  unsigned short* v_t     = (unsigned short*)(ws + (68ull  << 20)); // 4   [qkv-gemm, attn]
  unsigned short* a_bf    = (unsigned short*)(ws + (72ull  << 20)); // 16  [attn, quant_a]
  signed char*    a_i8    = (signed char*)   (ws + (88ull  << 20)); // 8   [quant_a, o-gemm]
  float*          sx      = (float*)         (ws + (128ull << 20)); // 8 KB
  float*          sa      = (float*)         (ws + (129ull << 20)); // 8 KB
  if (ws_size < (130ull << 20)) return;

  // fused weight-cvt (16-deep ILP) + activation-quant
  prep_all<<<4608, 256, 0, stream>>>(wq, wk, wv, wo, wqkv_i8, wo_i8, x, x_i8, sx);

  // QKV GEMM, full-K, fused epilogue -> q_bf / k_bf / v_t directly
  gemm_i8<0><<<dim3(NQKVD / 128, MR / 128), 256, 0, stream>>>(
      x_i8, wqkv_i8, sx, wqs, wks, wvs, bq, bk, q_bf, k_bf, v_t, nullptr);

  attn_kernel<<<dim3(16, NHH, BB), 256, 0, stream>>>(q_bf, k_bf, v_t, a_bf);

  quant_bf16<<<MR, 256, 0, stream>>>(a_bf, a_i8, sa);

  // O GEMM, full-K, writes final f32 output directly
  gemm_i8<1><<<dim3(HH / 128, MR / 128), 256, 0, stream>>>(
      a_i8, wo_i8, sa, wos, nullptr, nullptr, nullptr, nullptr,
      nullptr, nullptr, nullptr, out);
}

// Round 10
// 400.729 us; speedup vs baseline: 1.0159x; 1.0159x over previous
//
#include <hip/hip_runtime.h>
#include <math.h>

// Problem constants
#define BB   2
#define SS   1024
#define HH   4096
#define NHH  32
#define NKVV 8
#define HDD  128
#define MR   2048   // B*S
#define KVD  1024   // NKV*HD
#define NQKVD 6144  // H + 2*KVD
#define KD   4096
// 1/sqrt(128) * log2(e): attention scores produced directly in exp2 domain
#define SCALE2_F 0.12751744f

typedef __attribute__((ext_vector_type(8))) short bf16x8;
typedef __attribute__((ext_vector_type(4))) float f32x4;
typedef __attribute__((ext_vector_type(4))) int i32x4;

#define MFMA(a, b, c) __builtin_amdgcn_mfma_f32_16x16x32_bf16((a), (b), (c), 0, 0, 0)
#define MFMA_I8(a, b, c) __builtin_amdgcn_mfma_i32_16x16x64_i8((a), (b), (c), 0, 0, 0)

__device__ __forceinline__ unsigned short f2bf(float f) {
  union { float f; unsigned u; } v; v.f = f;
  return (unsigned short)((v.u + 0x7fffu + ((v.u >> 16) & 1u)) >> 16);
}
__device__ __forceinline__ float bf2f(unsigned short s) {
  union { unsigned u; float f; } v; v.u = ((unsigned)s) << 16; return v.f;
}
// 2^x via the hardware transcendental (v_exp_f32 IS exp2)
__device__ __forceinline__ float exp2_fast(float x) {
  float r; asm("v_exp_f32 %0, %1" : "=v"(r) : "v"(x)); return r;
}
// pack two f32 -> packed bf16 pair (lo = s0, hi = s1), single instruction
__device__ __forceinline__ unsigned cvt_pk_bf16(float a, float b) {
  unsigned r; asm("v_cvt_pk_bf16_f32 %0, %1, %2" : "=v"(r) : "v"(a), "v"(b)); return r;
}

__device__ __forceinline__ void gload_lds16(const void* g, void* l) {
  __builtin_amdgcn_global_load_lds(
      (const __attribute__((address_space(1))) void*)g,
      (__attribute__((address_space(3))) void*)l, 16, 0, 0);
}

__device__ __forceinline__ signed char q8(float x, float inv) {
  float r = rintf(x * inv);
  r = fmaxf(-127.f, fminf(127.f, r));
  return (signed char)(int)r;
}

// ---------------- fused prep: weight cvt (all 4 matrices) + activation quant ----------------
// Round 13 (kept): 16-deep ILP batch per thread (~16 loads in flight/wave) to
// lift the load/pack/store chain off the latency floor (rounds 7/8: coalescing
// change was a NULL at identical 81us/1.85TB/s with VGPR=16 -> ILP-starved).
// Weight blocks: 2560 x 4096 chunks (region boundaries divide 4096 ->
// block-uniform branch). Blocks [2560, 4608): x row-quant (proven body).
#define NQ4 ((size_t)HH * HH / 4)
#define NK4 ((size_t)KVD * HH / 4)
__global__ void prep_all(const int* __restrict__ wq, const int* __restrict__ wk,
                         const int* __restrict__ wv, const int* __restrict__ wo,
                         signed char* __restrict__ wqkv, signed char* __restrict__ wo8,
                         const float* __restrict__ x, signed char* __restrict__ x_i8,
                         float* __restrict__ scale) {
  __shared__ float wm[4];
  const int t = threadIdx.x;
  if (blockIdx.x < 2560) {
    const size_t c0 = (size_t)blockIdx.x * 4096;   // block-uniform region select
    const int4* src;
    unsigned* dst;
    size_t off0;
    if (c0 < NQ4) { src = (const int4*)wq; dst = (unsigned*)wqkv; off0 = c0; }
    else if (c0 < NQ4 + NK4) { src = (const int4*)wk; dst = (unsigned*)wqkv + NQ4; off0 = c0 - NQ4; }
    else if (c0 < NQ4 + 2 * NK4) { src = (const int4*)wv; dst = (unsigned*)wqkv + NQ4 + NK4; off0 = c0 - NQ4 - NK4; }
    else { src = (const int4*)wo; dst = (unsigned*)wo8; off0 = c0 - NQ4 - 2 * NK4; }
    off0 += t;
    int4 v[16];
#pragma unroll
    for (int j = 0; j < 16; ++j) v[j] = src[off0 + j * 256];   // 16 loads in flight
#pragma unroll
    for (int j = 0; j < 16; ++j)
      dst[off0 + j * 256] = (v[j].x & 0xff) | ((v[j].y & 0xff) << 8) |
                            ((v[j].z & 0xff) << 16) | (v[j].w << 24);
  } else {
    const int row = blockIdx.x - 2560;
    const float4* p = (const float4*)(x + (size_t)row * HH) + t * 4;
    float4 v[4];
    float m = 0.f;
#pragma unroll
    for (int j = 0; j < 4; ++j) {
      v[j] = p[j];
      m = fmaxf(m, fmaxf(fmaxf(fabsf(v[j].x), fabsf(v[j].y)), fmaxf(fabsf(v[j].z), fabsf(v[j].w))));
    }
#pragma unroll
    for (int o = 32; o; o >>= 1) m = fmaxf(m, __shfl_xor(m, o));
    if ((t & 63) == 0) wm[t >> 6] = m;
    __syncthreads();
    m = fmaxf(fmaxf(wm[0], wm[1]), fmaxf(wm[2], wm[3]));
    m = fmaxf(m, 1e-12f);
    const float inv = 127.f / m;
    union { signed char c[16]; int4 q; } o;
#pragma unroll
    for (int j = 0; j < 4; ++j) {
      o.c[j * 4 + 0] = q8(v[j].x, inv); o.c[j * 4 + 1] = q8(v[j].y, inv);
      o.c[j * 4 + 2] = q8(v[j].z, inv); o.c[j * 4 + 3] = q8(v[j].w, inv);
    }
    ((int4*)(x_i8 + (size_t)row * HH))[t] = o.q;
    if (t == 0) scale[row] = m / 127.f;
  }
}

__global__ void quant_bf16(const unsigned short* __restrict__ in, signed char* __restrict__ out,
                           float* __restrict__ scale) {
  __shared__ float wm[4];
  const int row = blockIdx.x;
  const int t = threadIdx.x;
  const uint4* p = (const uint4*)(in + (size_t)row * HH) + t * 2;
  float f[16];
  float m = 0.f;
#pragma unroll
  for (int j = 0; j < 2; ++j) {
    uint4 d = p[j];
    unsigned u[4] = {d.x, d.y, d.z, d.w};
#pragma unroll
    for (int k = 0; k < 4; ++k) {
      f[j * 8 + k * 2] = bf2f((unsigned short)(u[k] & 0xffff));
      f[j * 8 + k * 2 + 1] = bf2f((unsigned short)(u[k] >> 16));
    }
  }
#pragma unroll
  for (int e = 0; e < 16; ++e) m = fmaxf(m, fabsf(f[e]));
#pragma unroll
  for (int o = 32; o; o >>= 1) m = fmaxf(m, __shfl_xor(m, o));
  if ((t & 63) == 0) wm[t >> 6] = m;
  __syncthreads();
  m = fmaxf(fmaxf(wm[0], wm[1]), fmaxf(wm[2], wm[3]));
  m = fmaxf(m, 1e-12f);
  const float inv = 127.f / m;
  union { signed char c[16]; int4 q; } o;
#pragma unroll
  for (int e = 0; e < 16; ++e) o.c[e] = q8(f[e], inv);
  ((int4*)(out + (size_t)row * HH))[t] = o.q;
  if (t == 0) scale[row] = m / 127.f;
}

// ---------------- i8 GEMM, full-K, fused epilogue, STATIC counted-vmcnt dbuf ----------------
// Round 14: round-6's counted-vmcnt failed because asm("+v") offset-laundering
// forced DYNAMIC LDS addressing (VALU 19->34). This version unrolls the K-loop
// x2 with two LITERAL buffer offsets (0 / 16384) -> every ds_read offset folds
// to an immediate. Per 128-K step: STAGE(next) -> s_waitcnt vmcnt(8) (waits
// only the PREVIOUS stage's 8 loads; the 8 just issued stay in flight across
// the barrier) -> s_barrier -> COMPUTE(cur) -> release s_barrier. Race audit:
// a buffer is overwritten only after the release barrier every wave crosses
// post-read; per-wave loads are vmcnt-counted before the ready barrier;
// zero-cost "memory" asm fences pin stage/reads to the correct side of the
// raw barriers. LDS 64 KB (2 bufs).
// MODE 0: QKV fused epilogue (Q bias+scale, K bias, V transposed). MODE 1: O f32.
template <int MODE>
__global__ __launch_bounds__(256) void gemm_i8(
    const signed char* __restrict__ A, const signed char* __restrict__ W,
    const float* __restrict__ sRow,
    const float* __restrict__ s0, const float* __restrict__ s1, const float* __restrict__ s2,
    const float* __restrict__ bQ, const float* __restrict__ bK,
    unsigned short* __restrict__ oQ, unsigned short* __restrict__ oK,
    unsigned short* __restrict__ oVt, float* __restrict__ oF) {
  __shared__ signed char ldsA[2 * 128 * 128];
  __shared__ signed char ldsB[2 * 128 * 128];
  const int t = threadIdx.x;
  const int lane = t & 63;
  const int w = t >> 6;
  const int wr = w & 1, wc = w >> 1;
  const int l15 = lane & 15, quad = lane >> 4;
  const int bm = blockIdx.y, bn = blockIdx.x;

  const int srow_ = t >> 3;                          // 0..31
  const int scol_ = ((t & 7) ^ (srow_ & 7)) * 16;    // XOR-swizzled source column
  const signed char* gA = A + (size_t)(bm * 128 + srow_) * KD + scol_;
  const signed char* gW = W + (size_t)(bn * 128 + srow_) * KD + scol_;
  signed char* lA = ldsA + t * 16;  // wave base + lane*16 (global_load_lds layout rule)
  signed char* lB = ldsB + t * 16;

  i32x4 acc[4][4] = {};

  // stage one BK=128 tile (8 async loads/thread) into buffer at byte offset bo
  auto STAGE = [&](int bo, int k0) {
#pragma unroll
    for (int j = 0; j < 4; ++j) {
      gload_lds16(gA + (size_t)j * 32 * KD + k0, lA + bo + j * 4096);
      gload_lds16(gW + (size_t)j * 32 * KD + k0, lB + bo + j * 4096);
    }
  };
  // compute one BK=128 tile from buffer at LITERAL byte offset bo
  auto COMPUTE = [&](int bo) {
#pragma unroll
    for (int kc = 0; kc < 2; ++kc) {
      i32x4 af[4], bfr[4];
#pragma unroll
      for (int mi = 0; mi < 4; ++mi) {
        const int row = wr * 64 + mi * 16 + l15;
        const int ch = (kc * 4 + quad) ^ (row & 7);
        af[mi] = *(const i32x4*)(ldsA + bo + row * 128 + ch * 16);
      }
#pragma unroll
      for (int ni = 0; ni < 4; ++ni) {
        const int row = wc * 64 + ni * 16 + l15;
        const int ch = (kc * 4 + quad) ^ (row & 7);
        bfr[ni] = *(const i32x4*)(ldsB + bo + row * 128 + ch * 16);
      }
#pragma unroll
      for (int mi = 0; mi < 4; ++mi)
#pragma unroll
        for (int ni = 0; ni < 4; ++ni)
          acc[mi][ni] = MFMA_I8(af[mi], bfr[ni], acc[mi][ni]);
    }
  };

  STAGE(0, 0);
#pragma unroll 1
  for (int ti = 0; ti < KD / 256; ++ti) {
    const int kbase = ti * 256;
    // ---- step A: buf1 <- k+128, compute buf0 (k+0) ----
    STAGE(16384, kbase + 128);
    asm volatile("s_waitcnt vmcnt(8)" ::: "memory");  // prev stage's 8 done
    __builtin_amdgcn_s_barrier();                     // buf0 ready (all waves)
    asm volatile("" ::: "memory");
    COMPUTE(0);
    asm volatile("" ::: "memory");
    __builtin_amdgcn_s_barrier();                     // release buf0
    asm volatile("" ::: "memory");
    // ---- step B: buf0 <- k+256 (except last), compute buf1 (k+128) ----
    if (ti < KD / 256 - 1) {
      STAGE(0, kbase + 256);
      asm volatile("s_waitcnt vmcnt(8)" ::: "memory");
    } else {
      asm volatile("s_waitcnt vmcnt(0)" ::: "memory");
    }
    __builtin_amdgcn_s_barrier();                     // buf1 ready
    asm volatile("" ::: "memory");
    COMPUTE(16384);
    asm volatile("" ::: "memory");
    __builtin_amdgcn_s_barrier();                     // release buf1
    asm volatile("" ::: "memory");
  }

  // C/D layout: row = quad*4 + r, col = lane&15 (dtype-independent, m121-128)
  const int row0 = bm * 128 + wr * 64 + quad * 4;
  const int col0 = bn * 128 + wc * 64 + l15;
  if (MODE == 1) {
    // O-projection: write f32 final output directly
#pragma unroll
    for (int ni = 0; ni < 4; ++ni) {
      const int col = col0 + ni * 16;
      const float sc = s0[col];
#pragma unroll
      for (int mi = 0; mi < 4; ++mi)
#pragma unroll
        for (int r = 0; r < 4; ++r) {
          const int row = row0 + mi * 16 + r;
          oF[(size_t)row * HH + col] = (float)acc[mi][ni][r] * sRow[row] * sc;
        }
    }
  } else if (col0 < HH) {
    // Q region: (v + bias) * log2e/sqrt(d), bf16 (exp2-domain pre-scale)
#pragma unroll
    for (int ni = 0; ni < 4; ++ni) {
      const int col = col0 + ni * 16;
      const float sc = s0[col];
      const float bv = bQ[col];
#pragma unroll
      for (int mi = 0; mi < 4; ++mi)
#pragma unroll
        for (int r = 0; r < 4; ++r) {
          const int row = row0 + mi * 16 + r;
          oQ[(size_t)row * HH + col] =
              f2bf(((float)acc[mi][ni][r] * sRow[row] * sc + bv) * SCALE2_F);
        }
    }
  } else if (col0 < HH + KVD) {
    // K region: + bias, bf16
#pragma unroll
    for (int ni = 0; ni < 4; ++ni) {
      const int col = col0 + ni * 16;
      const float sc = s1[col - HH];
      const float bv = bK[col - HH];
#pragma unroll
      for (int mi = 0; mi < 4; ++mi)
#pragma unroll
        for (int r = 0; r < 4; ++r) {
          const int row = row0 + mi * 16 + r;
          oK[(size_t)row * KVD + (col - HH)] =
              f2bf((float)acc[mi][ni][r] * sRow[row] * sc + bv);
        }
    }
  } else {
    // V region: write TRANSPOSED into Vt[col][row]; lane's 4 r-rows are
    // consecutive -> one 8B store per (mi,ni) fragment.
#pragma unroll
    for (int ni = 0; ni < 4; ++ni) {
      const int c = col0 + ni * 16 - (HH + KVD);
      const float sc = s2[c];
#pragma unroll
      for (int mi = 0; mi < 4; ++mi) {
        union { unsigned short s[4]; unsigned long long d; } pk;
#pragma unroll
        for (int r = 0; r < 4; ++r) {
          const int row = row0 + mi * 16 + r;
          pk.s[r] = f2bf((float)acc[mi][ni][r] * sRow[row] * sc);
        }
        *(unsigned long long*)(oVt + (size_t)c * MR + row0 + mi * 16) = pk.d;
      }
    }
  }
}

// ---------------- flash attention: 4-wave blocks, 64-row Q tile ----------------
// Round-4 verified: softmax chain cuts (cvt_pk pack, exp2 domain, diagonal-only
// mask, defer-max THR=8, lane-local l, setprio) dropped attn out of the top-5
// (<69us from 78.5). Structure: single-barrier double-buffered K+V LDS pipeline.
// Q pre-scaled by log2e/sqrt(d) in the QKV gemm epilogue; scores are exp2-domain.
__global__ __launch_bounds__(256, 2) void attn_kernel(
    const unsigned short* __restrict__ Q,   // [2048][4096]
    const unsigned short* __restrict__ K,   // [2048][1024]
    const unsigned short* __restrict__ Vt,  // [1024][2048]
    unsigned short* __restrict__ O) {       // [2048][4096]
  __shared__ unsigned short ldsK[2][64][128];   // K tiles (source-swizzled), 32 KB
  __shared__ unsigned short ldsV[2][2 * 128 * 32];  // V tiles [kc][hd][32], 32 KB
  __shared__ unsigned short ldsP[4][16 * 88];   // per-wave P tile 11 KB
  const int t = threadIdx.x;
  const int lane = t & 63;
  const int wv = t >> 6;
  const int l15 = lane & 15, quad = lane >> 4;
  const int qt = 15 - blockIdx.x;  // heavy-first
  const int h = blockIdx.y;
  const int b = blockIdx.z;
  const int kv = h >> 2;
  const int q0w = qt * 64 + wv * 16;
  const int q = q0w + l15;

  bf16x8 bq[4];
  const unsigned short* qbase = Q + (size_t)(b * SS + q0w + l15) * HH + h * HDD + quad * 8;
#pragma unroll
  for (int kk = 0; kk < 4; ++kk) bq[kk] = *(const bf16x8*)(qbase + kk * 32);

  const int srow = t >> 4;                        // 0..15
  const int schunk = (t & 15) ^ (srow & 7);       // pre-swizzled source chunk
  const unsigned short* gK = K + (size_t)(b * SS + srow) * KVD + kv * HDD + schunk * 8;
  const unsigned short* gV = Vt + (size_t)(kv * HDD + wv * 32 + (lane >> 2)) * MR + b * SS + (lane & 3) * 8;
  unsigned short* lV = &ldsV[0][0] + wv * 1024 + lane * 8;
  unsigned short* lp = ldsP[wv];

  f32x4 accO[8] = {};
  float m_run = -1e30f, l_part = 0.f;

  // prologue: stage tile 0 (K and V) into buf 0 (__syncthreads drains vmcnt)
#pragma unroll
  for (int j = 0; j < 4; ++j)
    gload_lds16(gK + (size_t)j * 16 * KVD, &ldsK[0][j * 16][0] + t * 8);
#pragma unroll
  for (int kc = 0; kc < 2; ++kc)
#pragma unroll
    for (int j = 0; j < 2; ++j)
      gload_lds16(gV + (size_t)j * 16 * MR + kc * 32, lV + kc * 4096 + j * 512);
  __syncthreads();

  int cur = 0;
  for (int kt = 0; kt <= qt; ++kt) {
    const int k0 = kt * 64;
    // prefetch NEXT tile (K and V) into the other buffers
    if (kt < qt) {
#pragma unroll
      for (int j = 0; j < 4; ++j)
        gload_lds16(gK + (size_t)(k0 + 64 + j * 16) * KVD,
                    &ldsK[cur ^ 1][j * 16][0] + t * 8);
#pragma unroll
      for (int kc = 0; kc < 2; ++kc)
#pragma unroll
        for (int j = 0; j < 2; ++j)
          gload_lds16(gV + (size_t)j * 16 * MR + k0 + 64 + kc * 32,
                      lV + (cur ^ 1) * 8192 + kc * 4096 + j * 512);
    }

    // QK^T from ldsK[cur] (de-swizzled read)
    f32x4 st[4] = {};
    __builtin_amdgcn_s_setprio(1);
#pragma unroll
    for (int kk = 0; kk < 4; ++kk)
#pragma unroll
      for (int mf = 0; mf < 4; ++mf) {
        const int r = mf * 16 + l15;
        bf16x8 af = *(const bf16x8*)(&ldsK[cur][r][((kk * 4 + quad) ^ (r & 7)) * 8]);
        st[mf] = MFMA(af, bq[kk], st[mf]);
      }
    __builtin_amdgcn_s_setprio(0);

    float p[4][4];
#pragma unroll
    for (int mf = 0; mf < 4; ++mf)
#pragma unroll
      for (int r = 0; r < 4; ++r) p[mf][r] = st[mf][r];
    if (kt == qt) {  // causal mask only on the diagonal tile
#pragma unroll
      for (int mf = 0; mf < 4; ++mf)
#pragma unroll
        for (int r = 0; r < 4; ++r) {
          const int k = k0 + mf * 16 + quad * 4 + r;
          if (k > q) p[mf][r] = -1e30f;
        }
    }
    float cm = -1e30f;
#pragma unroll
    for (int mf = 0; mf < 4; ++mf)
#pragma unroll
      for (int r = 0; r < 4; ++r) cm = fmaxf(cm, p[mf][r]);
    cm = fmaxf(cm, __shfl_xor(cm, 16));
    cm = fmaxf(cm, __shfl_xor(cm, 32));

    // defer-max (T13): rescale only when some row's max grew past THR=8
    if (!__all(cm <= m_run + 8.f)) {
      const float mn = fmaxf(m_run, cm);
      const float al = exp2_fast(m_run - mn);
      l_part *= al;
      m_run = mn;
      float af4[4];
#pragma unroll
      for (int r = 0; r < 4; ++r) af4[r] = __shfl(al, quad * 4 + r);
#pragma unroll
      for (int cb = 0; cb < 8; ++cb)
#pragma unroll
        for (int r = 0; r < 4; ++r) accO[cb][r] *= af4[r];
    }

    // exp2 + lane-local l + cvt_pk pack (8 insts, was ~80)
#pragma unroll
    for (int mf = 0; mf < 4; ++mf) {
      const float e0 = exp2_fast(p[mf][0] - m_run);
      const float e1 = exp2_fast(p[mf][1] - m_run);
      const float e2 = exp2_fast(p[mf][2] - m_run);
      const float e3 = exp2_fast(p[mf][3] - m_run);
      l_part += (e0 + e1) + (e2 + e3);
      union { unsigned u[2]; unsigned long long d; } pk;
      pk.u[0] = cvt_pk_bf16(e0, e1);
      pk.u[1] = cvt_pk_bf16(e2, e3);
      *(unsigned long long*)(lp + l15 * 88 + mf * 16 + quad * 4) = pk.d;
    }
    bf16x8 ap0 = *(const bf16x8*)(lp + l15 * 88 + quad * 8);
    bf16x8 ap1 = *(const bf16x8*)(lp + l15 * 88 + 32 + quad * 8);

    // PV from ldsV[cur]
    __builtin_amdgcn_s_setprio(1);
#pragma unroll
    for (int cb = 0; cb < 8; ++cb) {
      bf16x8 bv0 = *(const bf16x8*)(&ldsV[cur][0] + (cb * 16 + l15) * 32 + quad * 8);
      bf16x8 bv1 = *(const bf16x8*)(&ldsV[cur][0] + 4096 + (cb * 16 + l15) * 32 + quad * 8);
      accO[cb] = MFMA(ap0, bv0, accO[cb]);
      accO[cb] = MFMA(ap1, bv1, accO[cb]);
    }
    __builtin_amdgcn_s_setprio(0);

    __syncthreads();
    cur ^= 1;
  }

  // final l reduce (once, not per tile)
  l_part += __shfl_xor(l_part, 16);
  l_part += __shfl_xor(l_part, 32);
  float lr[4];
#pragma unroll
  for (int r = 0; r < 4; ++r) lr[r] = __shfl(l_part, quad * 4 + r);
  unsigned short* ob = O + (size_t)(b * SS + q0w + quad * 4) * HH + h * HDD + l15;
#pragma unroll
  for (int cb = 0; cb < 8; ++cb)
#pragma unroll
    for (int r = 0; r < 4; ++r)
      ob[(size_t)r * HH + cb * 16] = f2bf(accO[cb][r] / lr[r]);
}

extern "C" void kernel_launch(void* const* d_in, const int* in_sizes, int n_in,
                              void* d_out, int out_size, void* d_ws, size_t ws_size,
                              hipStream_t stream) {
  const float* x = (const float*)d_in[0];
  const int* wq = (const int*)d_in[2];
  const float* wqs = (const float*)d_in[3];
  const float* bq = (const float*)d_in[4];
  const int* wk = (const int*)d_in[5];
  const float* wks = (const float*)d_in[6];
  const float* bk = (const float*)d_in[7];
  const int* wv = (const int*)d_in[8];
  const float* wvs = (const float*)d_in[9];
  const int* wo = (const int*)d_in[10];
  const float* wos = (const float*)d_in[11];
  float* out = (float*)d_out;
  char* ws = (char*)d_ws;

  // workspace (MiB offsets), overlap-free:
  signed char*    x_i8    = (signed char*)   (ws + (0ull   << 20)); // 8   [prep, qkv-gemm]
  signed char*    wqkv_i8 = (signed char*)   (ws + (8ull   << 20)); // 24  [prep, qkv-gemm]
  signed char*    wo_i8   = (signed char*)   (ws + (32ull  << 20)); // 16  [prep, o-gemm]
  unsigned short* q_bf    = (unsigned short*)(ws + (48ull  << 20)); // 16  [qkv-gemm, attn]
  unsigned short* k_bf    = (unsigned short*)(ws + (64ull  << 20)); // 4   [qkv-gemm, attn]
  unsigned short* v_t     = (unsigned short*)(ws + (68ull  << 20)); // 4   [qkv-gemm, attn]
  unsigned short* a_bf    = (unsigned short*)(ws + (72ull  << 20)); // 16  [attn, quant_a]
  signed char*    a_i8    = (signed char*)   (ws + (88ull  << 20)); // 8   [quant_a, o-gemm]
  float*          sx      = (float*)         (ws + (128ull << 20)); // 8 KB
  float*          sa      = (float*)         (ws + (129ull << 20)); // 8 KB
  if (ws_size < (130ull << 20)) return;

  // fused weight-cvt (16-deep ILP) + activation-quant
  prep_all<<<4608, 256, 0, stream>>>(wq, wk, wv, wo, wqkv_i8, wo_i8, x, x_i8, sx);

  // QKV GEMM, full-K, fused epilogue -> q_bf / k_bf / v_t directly
  gemm_i8<0><<<dim3(NQKVD / 128, MR / 128), 256, 0, stream>>>(
      x_i8, wqkv_i8, sx, wqs, wks, wvs, bq, bk, q_bf, k_bf, v_t, nullptr);

  attn_kernel<<<dim3(16, NHH, BB), 256, 0, stream>>>(q_bf, k_bf, v_t, a_bf);

  quant_bf16<<<MR, 256, 0, stream>>>(a_bf, a_i8, sa);

  // O GEMM, full-K, writes final f32 output directly
  gemm_i8<1><<<dim3(HH / 128, MR / 128), 256, 0, stream>>>(
      a_i8, wo_i8, sa, wos, nullptr, nullptr, nullptr, nullptr,
      nullptr, nullptr, nullptr, out);
}

// Round 11
// 384.332 us; speedup vs baseline: 1.0592x; 1.0427x over previous
//
#include <hip/hip_runtime.h>
#include <math.h>

// Problem constants
#define BB   2
#define SS   1024
#define HH   4096
#define NHH  32
#define NKVV 8
#define HDD  128
#define MR   2048   // B*S
#define KVD  1024   // NKV*HD
#define NQKVD 6144  // H + 2*KVD
#define KD   4096
// 1/sqrt(128) * log2(e): attention scores produced directly in exp2 domain
#define SCALE2_F 0.12751744f

typedef __attribute__((ext_vector_type(8))) short bf16x8;
typedef __attribute__((ext_vector_type(4))) float f32x4;
typedef __attribute__((ext_vector_type(4))) int i32x4;

#define MFMA(a, b, c) __builtin_amdgcn_mfma_f32_16x16x32_bf16((a), (b), (c), 0, 0, 0)
#define MFMA_I8(a, b, c) __builtin_amdgcn_mfma_i32_16x16x64_i8((a), (b), (c), 0, 0, 0)

__device__ __forceinline__ unsigned short f2bf(float f) {
  union { float f; unsigned u; } v; v.f = f;
  return (unsigned short)((v.u + 0x7fffu + ((v.u >> 16) & 1u)) >> 16);
}
__device__ __forceinline__ float bf2f(unsigned short s) {
  union { unsigned u; float f; } v; v.u = ((unsigned)s) << 16; return v.f;
}
// 2^x via the hardware transcendental (v_exp_f32 IS exp2)
__device__ __forceinline__ float exp2_fast(float x) {
  float r; asm("v_exp_f32 %0, %1" : "=v"(r) : "v"(x)); return r;
}
// pack two f32 -> packed bf16 pair (lo = s0, hi = s1), single instruction
__device__ __forceinline__ unsigned cvt_pk_bf16(float a, float b) {
  unsigned r; asm("v_cvt_pk_bf16_f32 %0, %1, %2" : "=v"(r) : "v"(a), "v"(b)); return r;
}

__device__ __forceinline__ void gload_lds16(const void* g, void* l) {
  __builtin_amdgcn_global_load_lds(
      (const __attribute__((address_space(1))) void*)g,
      (__attribute__((address_space(3))) void*)l, 16, 0, 0);
}

__device__ __forceinline__ signed char q8(float x, float inv) {
  float r = rintf(x * inv);
  r = fmaxf(-127.f, fminf(127.f, r));
  return (signed char)(int)r;
}

__device__ __forceinline__ unsigned pack_i32x4(int4 v) {
  return (v.x & 0xff) | ((v.y & 0xff) << 8) | ((v.z & 0xff) << 16) | (v.w << 24);
}

// ---------------- prep: QKV weight cvt + activation quant (wo rides in attn) ----------------
// Rounds 7/8/10: three access-pattern variants (64B-stride, coalesced, 16-deep
// ILP) all land at 80-85us / ~2.9 TB/s logical -> streaming wall, not pattern.
// Round 15: shrink prep's critical-path traffic instead. wo (67MB read + 17MB
// write, needed only by the O-GEMM) moves into attn_kernel's dispatch as rider
// blocks (attn runs at 8% HBM / 15% occupancy -> free BW window). prep keeps
// x-quant + wq/wk/wv.
// Blocks [0,1536): wqkv cvt (wq 1024 | wk 256 | wv 256 -- block-uniform).
// Blocks [1536,3584): x row-quant (proven body).
#define NQ4 ((size_t)HH * HH / 4)
#define NK4 ((size_t)KVD * HH / 4)
__global__ void prep_all(const int* __restrict__ wq, const int* __restrict__ wk,
                         const int* __restrict__ wv,
                         signed char* __restrict__ wqkv,
                         const float* __restrict__ x, signed char* __restrict__ x_i8,
                         float* __restrict__ scale) {
  __shared__ float wm[4];
  const int t = threadIdx.x;
  if (blockIdx.x < 1536) {
    const size_t c0 = (size_t)blockIdx.x * 4096;   // block-uniform region select
    const int4* src;
    unsigned* dst;
    size_t off0;
    if (c0 < NQ4) { src = (const int4*)wq; dst = (unsigned*)wqkv; off0 = c0; }
    else if (c0 < NQ4 + NK4) { src = (const int4*)wk; dst = (unsigned*)wqkv + NQ4; off0 = c0 - NQ4; }
    else { src = (const int4*)wv; dst = (unsigned*)wqkv + NQ4 + NK4; off0 = c0 - NQ4 - NK4; }
    off0 += t;
    int4 v[16];
#pragma unroll
    for (int j = 0; j < 16; ++j) v[j] = src[off0 + j * 256];
#pragma unroll
    for (int j = 0; j < 16; ++j) dst[off0 + j * 256] = pack_i32x4(v[j]);
  } else {
    const int row = blockIdx.x - 1536;
    const float4* p = (const float4*)(x + (size_t)row * HH) + t * 4;
    float4 v[4];
    float m = 0.f;
#pragma unroll
    for (int j = 0; j < 4; ++j) {
      v[j] = p[j];
      m = fmaxf(m, fmaxf(fmaxf(fabsf(v[j].x), fabsf(v[j].y)), fmaxf(fabsf(v[j].z), fabsf(v[j].w))));
    }
#pragma unroll
    for (int o = 32; o; o >>= 1) m = fmaxf(m, __shfl_xor(m, o));
    if ((t & 63) == 0) wm[t >> 6] = m;
    __syncthreads();
    m = fmaxf(fmaxf(wm[0], wm[1]), fmaxf(wm[2], wm[3]));
    m = fmaxf(m, 1e-12f);
    const float inv = 127.f / m;
    union { signed char c[16]; int4 q; } o;
#pragma unroll
    for (int j = 0; j < 4; ++j) {
      o.c[j * 4 + 0] = q8(v[j].x, inv); o.c[j * 4 + 1] = q8(v[j].y, inv);
      o.c[j * 4 + 2] = q8(v[j].z, inv); o.c[j * 4 + 3] = q8(v[j].w, inv);
    }
    ((int4*)(x_i8 + (size_t)row * HH))[t] = o.q;
    if (t == 0) scale[row] = m / 127.f;
  }
}

__global__ void quant_bf16(const unsigned short* __restrict__ in, signed char* __restrict__ out,
                           float* __restrict__ scale) {
  __shared__ float wm[4];
  const int row = blockIdx.x;
  const int t = threadIdx.x;
  const uint4* p = (const uint4*)(in + (size_t)row * HH) + t * 2;
  float f[16];
  float m = 0.f;
#pragma unroll
  for (int j = 0; j < 2; ++j) {
    uint4 d = p[j];
    unsigned u[4] = {d.x, d.y, d.z, d.w};
#pragma unroll
    for (int k = 0; k < 4; ++k) {
      f[j * 8 + k * 2] = bf2f((unsigned short)(u[k] & 0xffff));
      f[j * 8 + k * 2 + 1] = bf2f((unsigned short)(u[k] >> 16));
    }
  }
#pragma unroll
  for (int e = 0; e < 16; ++e) m = fmaxf(m, fabsf(f[e]));
#pragma unroll
  for (int o = 32; o; o >>= 1) m = fmaxf(m, __shfl_xor(m, o));
  if ((t & 63) == 0) wm[t >> 6] = m;
  __syncthreads();
  m = fmaxf(fmaxf(wm[0], wm[1]), fmaxf(wm[2], wm[3]));
  m = fmaxf(m, 1e-12f);
  const float inv = 127.f / m;
  union { signed char c[16]; int4 q; } o;
#pragma unroll
  for (int e = 0; e < 16; ++e) o.c[e] = q8(f[e], inv);
  ((int4*)(out + (size_t)row * HH))[t] = o.q;
  if (t == 0) scale[row] = m / 127.f;
}

// ---------------- i8 GEMM, full-K, fused epilogue, STATIC counted-vmcnt dbuf ----------------
// Round-9/10: this static-offset counted-vmcnt form runs at parity-or-better
// vs the 2-barrier form (cross-session clock noise masked the exact delta;
// round-10 shows it below 84.6us). Literal buffer offsets (0/16384) keep every
// ds_read offset an immediate (round-6's asm("+v") failure mode avoided).
// Per 128-K step: STAGE(next) -> vmcnt(8) (waits only the PREVIOUS stage's
// loads) -> barrier -> COMPUTE -> release barrier. LDS 64 KB.
// MODE 0: QKV fused epilogue (Q bias+scale, K bias, V transposed). MODE 1: O f32.
template <int MODE>
__global__ __launch_bounds__(256) void gemm_i8(
    const signed char* __restrict__ A, const signed char* __restrict__ W,
    const float* __restrict__ sRow,
    const float* __restrict__ s0, const float* __restrict__ s1, const float* __restrict__ s2,
    const float* __restrict__ bQ, const float* __restrict__ bK,
    unsigned short* __restrict__ oQ, unsigned short* __restrict__ oK,
    unsigned short* __restrict__ oVt, float* __restrict__ oF) {
  __shared__ signed char ldsA[2 * 128 * 128];
  __shared__ signed char ldsB[2 * 128 * 128];
  const int t = threadIdx.x;
  const int lane = t & 63;
  const int w = t >> 6;
  const int wr = w & 1, wc = w >> 1;
  const int l15 = lane & 15, quad = lane >> 4;
  const int bm = blockIdx.y, bn = blockIdx.x;

  const int srow_ = t >> 3;                          // 0..31
  const int scol_ = ((t & 7) ^ (srow_ & 7)) * 16;    // XOR-swizzled source column
  const signed char* gA = A + (size_t)(bm * 128 + srow_) * KD + scol_;
  const signed char* gW = W + (size_t)(bn * 128 + srow_) * KD + scol_;
  signed char* lA = ldsA + t * 16;  // wave base + lane*16 (global_load_lds layout rule)
  signed char* lB = ldsB + t * 16;

  i32x4 acc[4][4] = {};

  auto STAGE = [&](int bo, int k0) {
#pragma unroll
    for (int j = 0; j < 4; ++j) {
      gload_lds16(gA + (size_t)j * 32 * KD + k0, lA + bo + j * 4096);
      gload_lds16(gW + (size_t)j * 32 * KD + k0, lB + bo + j * 4096);
    }
  };
  auto COMPUTE = [&](int bo) {
#pragma unroll
    for (int kc = 0; kc < 2; ++kc) {
      i32x4 af[4], bfr[4];
#pragma unroll
      for (int mi = 0; mi < 4; ++mi) {
        const int row = wr * 64 + mi * 16 + l15;
        const int ch = (kc * 4 + quad) ^ (row & 7);
        af[mi] = *(const i32x4*)(ldsA + bo + row * 128 + ch * 16);
      }
#pragma unroll
      for (int ni = 0; ni < 4; ++ni) {
        const int row = wc * 64 + ni * 16 + l15;
        const int ch = (kc * 4 + quad) ^ (row & 7);
        bfr[ni] = *(const i32x4*)(ldsB + bo + row * 128 + ch * 16);
      }
#pragma unroll
      for (int mi = 0; mi < 4; ++mi)
#pragma unroll
        for (int ni = 0; ni < 4; ++ni)
          acc[mi][ni] = MFMA_I8(af[mi], bfr[ni], acc[mi][ni]);
    }
  };

  STAGE(0, 0);
#pragma unroll 1
  for (int ti = 0; ti < KD / 256; ++ti) {
    const int kbase = ti * 256;
    STAGE(16384, kbase + 128);
    asm volatile("s_waitcnt vmcnt(8)" ::: "memory");
    __builtin_amdgcn_s_barrier();
    asm volatile("" ::: "memory");
    COMPUTE(0);
    asm volatile("" ::: "memory");
    __builtin_amdgcn_s_barrier();
    asm volatile("" ::: "memory");
    if (ti < KD / 256 - 1) {
      STAGE(0, kbase + 256);
      asm volatile("s_waitcnt vmcnt(8)" ::: "memory");
    } else {
      asm volatile("s_waitcnt vmcnt(0)" ::: "memory");
    }
    __builtin_amdgcn_s_barrier();
    asm volatile("" ::: "memory");
    COMPUTE(16384);
    asm volatile("" ::: "memory");
    __builtin_amdgcn_s_barrier();
    asm volatile("" ::: "memory");
  }

  // C/D layout: row = quad*4 + r, col = lane&15 (dtype-independent, m121-128)
  const int row0 = bm * 128 + wr * 64 + quad * 4;
  const int col0 = bn * 128 + wc * 64 + l15;
  if (MODE == 1) {
#pragma unroll
    for (int ni = 0; ni < 4; ++ni) {
      const int col = col0 + ni * 16;
      const float sc = s0[col];
#pragma unroll
      for (int mi = 0; mi < 4; ++mi)
#pragma unroll
        for (int r = 0; r < 4; ++r) {
          const int row = row0 + mi * 16 + r;
          oF[(size_t)row * HH + col] = (float)acc[mi][ni][r] * sRow[row] * sc;
        }
    }
  } else if (col0 < HH) {
#pragma unroll
    for (int ni = 0; ni < 4; ++ni) {
      const int col = col0 + ni * 16;
      const float sc = s0[col];
      const float bv = bQ[col];
#pragma unroll
      for (int mi = 0; mi < 4; ++mi)
#pragma unroll
        for (int r = 0; r < 4; ++r) {
          const int row = row0 + mi * 16 + r;
          oQ[(size_t)row * HH + col] =
              f2bf(((float)acc[mi][ni][r] * sRow[row] * sc + bv) * SCALE2_F);
        }
    }
  } else if (col0 < HH + KVD) {
#pragma unroll
    for (int ni = 0; ni < 4; ++ni) {
      const int col = col0 + ni * 16;
      const float sc = s1[col - HH];
      const float bv = bK[col - HH];
#pragma unroll
      for (int mi = 0; mi < 4; ++mi)
#pragma unroll
        for (int r = 0; r < 4; ++r) {
          const int row = row0 + mi * 16 + r;
          oK[(size_t)row * KVD + (col - HH)] =
              f2bf((float)acc[mi][ni][r] * sRow[row] * sc + bv);
        }
    }
  } else {
#pragma unroll
    for (int ni = 0; ni < 4; ++ni) {
      const int c = col0 + ni * 16 - (HH + KVD);
      const float sc = s2[c];
#pragma unroll
      for (int mi = 0; mi < 4; ++mi) {
        union { unsigned short s[4]; unsigned long long d; } pk;
#pragma unroll
        for (int r = 0; r < 4; ++r) {
          const int row = row0 + mi * 16 + r;
          pk.s[r] = f2bf((float)acc[mi][ni][r] * sRow[row] * sc);
        }
        *(unsigned long long*)(oVt + (size_t)c * MR + row0 + mi * 16) = pk.d;
      }
    }
  }
}

// ---------------- flash attention + wo-cvt rider blocks ----------------
// Round 15: attn runs at 8% HBM / 15% occupancy -> free BW window. Grid z
// extended 2->4; blocks with z>=BB convert wo int32->int8 (67MB read + 17MB
// write ridden under attn's idle BW, off prep's serial critical path). The
// rider path has no barriers; attn path's __syncthreads are per-block -> safe.
// wo_i8 is consumed by the O-GEMM which launches after attn completes.
// Attn structure (round-4 verified): single-barrier double-buffered K+V LDS
// pipeline; cvt_pk pack, exp2 domain, diagonal-only mask, defer-max THR=8,
// lane-local l, setprio. Q pre-scaled by log2e/sqrt(d) in the QKV epilogue.
__global__ __launch_bounds__(256, 2) void attn_kernel(
    const unsigned short* __restrict__ Q,   // [2048][4096]
    const unsigned short* __restrict__ K,   // [2048][1024]
    const unsigned short* __restrict__ Vt,  // [1024][2048]
    unsigned short* __restrict__ O,         // [2048][4096]
    const int* __restrict__ wo, signed char* __restrict__ wo8) {
  __shared__ unsigned short ldsK[2][64][128];   // K tiles (source-swizzled), 32 KB
  __shared__ unsigned short ldsV[2][2 * 128 * 32];  // V tiles [kc][hd][32], 32 KB
  __shared__ unsigned short ldsP[4][16 * 88];   // per-wave P tile 11 KB
  const int t = threadIdx.x;
  const int bz = blockIdx.z;
  if (bz >= BB) {
    // ---- wo cvt rider: 1024 blocks x 4096 int4 chunks ----
    const int id = (bz - BB) * (16 * NHH) + blockIdx.y * 16 + blockIdx.x;  // 0..1023
    size_t off0 = (size_t)id * 4096 + t;
    const int4* src = (const int4*)wo;
    unsigned* dst = (unsigned*)wo8;
    int4 v[16];
#pragma unroll
    for (int j = 0; j < 16; ++j) v[j] = src[off0 + j * 256];
#pragma unroll
    for (int j = 0; j < 16; ++j) dst[off0 + j * 256] = pack_i32x4(v[j]);
    return;
  }
  const int lane = t & 63;
  const int wv = t >> 6;
  const int l15 = lane & 15, quad = lane >> 4;
  const int qt = 15 - blockIdx.x;  // heavy-first
  const int h = blockIdx.y;
  const int b = bz;
  const int kv = h >> 2;
  const int q0w = qt * 64 + wv * 16;
  const int q = q0w + l15;

  bf16x8 bq[4];
  const unsigned short* qbase = Q + (size_t)(b * SS + q0w + l15) * HH + h * HDD + quad * 8;
#pragma unroll
  for (int kk = 0; kk < 4; ++kk) bq[kk] = *(const bf16x8*)(qbase + kk * 32);

  const int srow = t >> 4;                        // 0..15
  const int schunk = (t & 15) ^ (srow & 7);       // pre-swizzled source chunk
  const unsigned short* gK = K + (size_t)(b * SS + srow) * KVD + kv * HDD + schunk * 8;
  const unsigned short* gV = Vt + (size_t)(kv * HDD + wv * 32 + (lane >> 2)) * MR + b * SS + (lane & 3) * 8;
  unsigned short* lV = &ldsV[0][0] + wv * 1024 + lane * 8;
  unsigned short* lp = ldsP[wv];

  f32x4 accO[8] = {};
  float m_run = -1e30f, l_part = 0.f;

  // prologue: stage tile 0 (K and V) into buf 0 (__syncthreads drains vmcnt)
#pragma unroll
  for (int j = 0; j < 4; ++j)
    gload_lds16(gK + (size_t)j * 16 * KVD, &ldsK[0][j * 16][0] + t * 8);
#pragma unroll
  for (int kc = 0; kc < 2; ++kc)
#pragma unroll
    for (int j = 0; j < 2; ++j)
      gload_lds16(gV + (size_t)j * 16 * MR + kc * 32, lV + kc * 4096 + j * 512);
  __syncthreads();

  int cur = 0;
  for (int kt = 0; kt <= qt; ++kt) {
    const int k0 = kt * 64;
    // prefetch NEXT tile (K and V) into the other buffers
    if (kt < qt) {
#pragma unroll
      for (int j = 0; j < 4; ++j)
        gload_lds16(gK + (size_t)(k0 + 64 + j * 16) * KVD,
                    &ldsK[cur ^ 1][j * 16][0] + t * 8);
#pragma unroll
      for (int kc = 0; kc < 2; ++kc)
#pragma unroll
        for (int j = 0; j < 2; ++j)
          gload_lds16(gV + (size_t)j * 16 * MR + k0 + 64 + kc * 32,
                      lV + (cur ^ 1) * 8192 + kc * 4096 + j * 512);
    }

    // QK^T from ldsK[cur] (de-swizzled read)
    f32x4 st[4] = {};
    __builtin_amdgcn_s_setprio(1);
#pragma unroll
    for (int kk = 0; kk < 4; ++kk)
#pragma unroll
      for (int mf = 0; mf < 4; ++mf) {
        const int r = mf * 16 + l15;
        bf16x8 af = *(const bf16x8*)(&ldsK[cur][r][((kk * 4 + quad) ^ (r & 7)) * 8]);
        st[mf] = MFMA(af, bq[kk], st[mf]);
      }
    __builtin_amdgcn_s_setprio(0);

    float p[4][4];
#pragma unroll
    for (int mf = 0; mf < 4; ++mf)
#pragma unroll
      for (int r = 0; r < 4; ++r) p[mf][r] = st[mf][r];
    if (kt == qt) {  // causal mask only on the diagonal tile
#pragma unroll
      for (int mf = 0; mf < 4; ++mf)
#pragma unroll
        for (int r = 0; r < 4; ++r) {
          const int k = k0 + mf * 16 + quad * 4 + r;
          if (k > q) p[mf][r] = -1e30f;
        }
    }
    float cm = -1e30f;
#pragma unroll
    for (int mf = 0; mf < 4; ++mf)
#pragma unroll
      for (int r = 0; r < 4; ++r) cm = fmaxf(cm, p[mf][r]);
    cm = fmaxf(cm, __shfl_xor(cm, 16));
    cm = fmaxf(cm, __shfl_xor(cm, 32));

    // defer-max (T13): rescale only when some row's max grew past THR=8
    if (!__all(cm <= m_run + 8.f)) {
      const float mn = fmaxf(m_run, cm);
      const float al = exp2_fast(m_run - mn);
      l_part *= al;
      m_run = mn;
      float af4[4];
#pragma unroll
      for (int r = 0; r < 4; ++r) af4[r] = __shfl(al, quad * 4 + r);
#pragma unroll
      for (int cb = 0; cb < 8; ++cb)
#pragma unroll
        for (int r = 0; r < 4; ++r) accO[cb][r] *= af4[r];
    }

    // exp2 + lane-local l + cvt_pk pack (8 insts, was ~80)
#pragma unroll
    for (int mf = 0; mf < 4; ++mf) {
      const float e0 = exp2_fast(p[mf][0] - m_run);
      const float e1 = exp2_fast(p[mf][1] - m_run);
      const float e2 = exp2_fast(p[mf][2] - m_run);
      const float e3 = exp2_fast(p[mf][3] - m_run);
      l_part += (e0 + e1) + (e2 + e3);
      union { unsigned u[2]; unsigned long long d; } pk;
      pk.u[0] = cvt_pk_bf16(e0, e1);
      pk.u[1] = cvt_pk_bf16(e2, e3);
      *(unsigned long long*)(lp + l15 * 88 + mf * 16 + quad * 4) = pk.d;
    }
    bf16x8 ap0 = *(const bf16x8*)(lp + l15 * 88 + quad * 8);
    bf16x8 ap1 = *(const bf16x8*)(lp + l15 * 88 + 32 + quad * 8);

    // PV from ldsV[cur]
    __builtin_amdgcn_s_setprio(1);
#pragma unroll
    for (int cb = 0; cb < 8; ++cb) {
      bf16x8 bv0 = *(const bf16x8*)(&ldsV[cur][0] + (cb * 16 + l15) * 32 + quad * 8);
      bf16x8 bv1 = *(const bf16x8*)(&ldsV[cur][0] + 4096 + (cb * 16 + l15) * 32 + quad * 8);
      accO[cb] = MFMA(ap0, bv0, accO[cb]);
      accO[cb] = MFMA(ap1, bv1, accO[cb]);
    }
    __builtin_amdgcn_s_setprio(0);

    __syncthreads();
    cur ^= 1;
  }

  // final l reduce (once, not per tile)
  l_part += __shfl_xor(l_part, 16);
  l_part += __shfl_xor(l_part, 32);
  float lr[4];
#pragma unroll
  for (int r = 0; r < 4; ++r) lr[r] = __shfl(l_part, quad * 4 + r);
  unsigned short* ob = O + (size_t)(b * SS + q0w + quad * 4) * HH + h * HDD + l15;
#pragma unroll
  for (int cb = 0; cb < 8; ++cb)
#pragma unroll
    for (int r = 0; r < 4; ++r)
      ob[(size_t)r * HH + cb * 16] = f2bf(accO[cb][r] / lr[r]);
}

extern "C" void kernel_launch(void* const* d_in, const int* in_sizes, int n_in,
                              void* d_out, int out_size, void* d_ws, size_t ws_size,
                              hipStream_t stream) {
  const float* x = (const float*)d_in[0];
  const int* wq = (const int*)d_in[2];
  const float* wqs = (const float*)d_in[3];
  const float* bq = (const float*)d_in[4];
  const int* wk = (const int*)d_in[5];
  const float* wks = (const float*)d_in[6];
  const float* bk = (const float*)d_in[7];
  const int* wv = (const int*)d_in[8];
  const float* wvs = (const float*)d_in[9];
  const int* wo = (const int*)d_in[10];
  const float* wos = (const float*)d_in[11];
  float* out = (float*)d_out;
  char* ws = (char*)d_ws;

  // workspace (MiB offsets), overlap-free:
  signed char*    x_i8    = (signed char*)   (ws + (0ull   << 20)); // 8   [prep, qkv-gemm]
  signed char*    wqkv_i8 = (signed char*)   (ws + (8ull   << 20)); // 24  [prep, qkv-gemm]
  signed char*    wo_i8   = (signed char*)   (ws + (32ull  << 20)); // 16  [attn-rider, o-gemm]
  unsigned short* q_bf    = (unsigned short*)(ws + (48ull  << 20)); // 16  [qkv-gemm, attn]
  unsigned short* k_bf    = (unsigned short*)(ws + (64ull  << 20)); // 4   [qkv-gemm, attn]
  unsigned short* v_t     = (unsigned short*)(ws + (68ull  << 20)); // 4   [qkv-gemm, attn]
  unsigned short* a_bf    = (unsigned short*)(ws + (72ull  << 20)); // 16  [attn, quant_a]
  signed char*    a_i8    = (signed char*)   (ws + (88ull  << 20)); // 8   [quant_a, o-gemm]
  float*          sx      = (float*)         (ws + (128ull << 20)); // 8 KB
  float*          sa      = (float*)         (ws + (129ull << 20)); // 8 KB
  if (ws_size < (130ull << 20)) return;

  // prep: x-quant + wq/wk/wv cvt (wo rides in attn)
  prep_all<<<3584, 256, 0, stream>>>(wq, wk, wv, wqkv_i8, x, x_i8, sx);

  // QKV GEMM, full-K, fused epilogue -> q_bf / k_bf / v_t directly
  gemm_i8<0><<<dim3(NQKVD / 128, MR / 128), 256, 0, stream>>>(
      x_i8, wqkv_i8, sx, wqs, wks, wvs, bq, bk, q_bf, k_bf, v_t, nullptr);

  // attn + wo-cvt rider blocks (z >= BB)
  attn_kernel<<<dim3(16, NHH, BB + 2), 256, 0, stream>>>(
      q_bf, k_bf, v_t, a_bf, wo, wo_i8);

  quant_bf16<<<MR, 256, 0, stream>>>(a_bf, a_i8, sa);

  // O GEMM, full-K, writes final f32 output directly
  gemm_i8<1><<<dim3(HH / 128, MR / 128), 256, 0, stream>>>(
      a_i8, wo_i8, sa, wos, nullptr, nullptr, nullptr, nullptr,
      nullptr, nullptr, nullptr, out);
}